// Round 5
// baseline (467.774 us; speedup 1.0000x reference)
//
#include <hip/hip_runtime.h>
#include <hip/hip_bf16.h>

#define HWsz 16384
#define Cdim 64
#define HIDd 128
#define NEXP 4
#define NBAT 16

typedef _Float16 h8 __attribute__((ext_vector_type(8)));
typedef _Float16 h4 __attribute__((ext_vector_type(4)));
typedef float f4 __attribute__((ext_vector_type(4)));

// d_ws layout (bytes)
#define OFF_W1F 0        // 4*128*64 f16   = 65536 B
#define OFF_W2F 65536    // 4*128*128 f16  = 131072 B
#define OFF_W3F 196608   // 4*64*128 f16   = 65536 B
#define OFF_B1F 262144   // 4*128 f32      = 2048 B
#define OFF_B2F 264192   // 4*128 f32      = 2048 B
#define OFF_B3F 266240   // 4*64 f32       = 1024 B
#define OFF_GAP 267264   // 16*64 f32      = 4096 B
#define OFF_GIDX 271360  // 16*2 int       = 128 B
#define OFF_GW  271488   // 16*2 f32       = 128 B
#define OFF_CNT 271616   // 1 int (gap-completion counter, memset to 0 per launch)

// pin a 16B fragment in VGPRs (forbid sinking/remat of the producing load)
__device__ __forceinline__ void pinv(f4& v) { asm volatile("" : "+v"(v)); }

// ---------------- prep: BN-fold/f16-cast + gap + (fused) gate ----------------
// blocks 0..1023: gap over x (b*64+c per block); the LAST gap block to finish
// also computes the gate (softmax+top2+aux) — device-scope atomics per G16.
// blocks 1024..1541: weight fold.
__global__ void prep_k(const float* __restrict__ x, float* __restrict__ gap,
                       const float* __restrict__ W1, const float* __restrict__ b1,
                       const float* __restrict__ g1, const float* __restrict__ be1,
                       const float* __restrict__ m1, const float* __restrict__ v1,
                       const float* __restrict__ W2, const float* __restrict__ b2,
                       const float* __restrict__ g2, const float* __restrict__ be2,
                       const float* __restrict__ m2, const float* __restrict__ v2,
                       const float* __restrict__ W3, const float* __restrict__ b3,
                       _Float16* __restrict__ W1f, _Float16* __restrict__ W2f,
                       _Float16* __restrict__ W3f,
                       float* __restrict__ b1f, float* __restrict__ b2f,
                       float* __restrict__ b3f,
                       const float* __restrict__ gwt, const float* __restrict__ gb,
                       int* __restrict__ gidx, float* __restrict__ gwo,
                       float* __restrict__ aux, int* __restrict__ cnt)
{
  const int t = threadIdx.x;             // 256
  if (blockIdx.x < 1024) {
    // ---- global average pool over one (b,c) row — 16 loads in flight
    const int bc = blockIdx.x;
    const float4* p4 = (const float4*)(x + (size_t)bc * HWsz);
    float s0 = 0.f, s1 = 0.f, s2 = 0.f, s3 = 0.f;
#pragma unroll
    for (int i = t; i < 4096; i += 1024) {
      const float4 a = p4[i], b4 = p4[i + 256], c4 = p4[i + 512], d4 = p4[i + 768];
      s0 += a.x + a.y + a.z + a.w;
      s1 += b4.x + b4.y + b4.z + b4.w;
      s2 += c4.x + c4.y + c4.z + c4.w;
      s3 += d4.x + d4.y + d4.z + d4.w;
    }
    float s = s0 + s1 + s2 + s3;
    for (int off = 32; off; off >>= 1) s += __shfl_down(s, off, 64);
    __shared__ float red[4];
    __shared__ int lastFlag;
    if ((t & 63) == 0) red[t >> 6] = s;
    __syncthreads();
    if (t == 0) {
      const float val = (red[0] + red[1] + red[2] + red[3]) * (1.0f / HWsz);
      __hip_atomic_store(&gap[bc], val, __ATOMIC_RELEASE, __HIP_MEMORY_SCOPE_AGENT);
      const int old = __hip_atomic_fetch_add(cnt, 1, __ATOMIC_ACQ_REL, __HIP_MEMORY_SCOPE_AGENT);
      lastFlag = (old == 1023) ? 1 : 0;
    }
    __syncthreads();
    if (lastFlag) {
      // ---- gate (runs once, in the last-finishing gap block)
      __shared__ float logits[NBAT][NEXP];
      __shared__ float gated[NBAT][NEXP];
      if (t < 64) {
        const int b = t >> 2, e = t & 3;
        float s2g = gb[e];
        for (int c = 0; c < Cdim; c++) {
          const float gv = __hip_atomic_load(&gap[b * Cdim + c], __ATOMIC_RELAXED,
                                             __HIP_MEMORY_SCOPE_AGENT);
          s2g += gv * gwt[e * Cdim + c];
        }
        logits[b][e] = s2g;
      }
      __syncthreads();
      if (t < NBAT) {
        const int b = t;
        float p[NEXP];
        float mx = logits[b][0];
        for (int e = 1; e < NEXP; e++) mx = fmaxf(mx, logits[b][e]);
        float sum = 0.f;
        for (int e = 0; e < NEXP; e++) { p[e] = expf(logits[b][e] - mx); sum += p[e]; }
        for (int e = 0; e < NEXP; e++) p[e] /= sum;
        int i0 = 0;
        for (int e = 1; e < NEXP; e++) if (p[e] > p[i0]) i0 = e;  // ties -> lower idx
        int i1 = (i0 == 0) ? 1 : 0;
        for (int e = 0; e < NEXP; e++) if (e != i0 && p[e] > p[i1]) i1 = e;
        const float s2 = p[i0] + p[i1] + 1e-8f;
        const float w0 = p[i0] / s2, w1 = p[i1] / s2;
        gidx[2 * b] = i0; gidx[2 * b + 1] = i1;
        gwo[2 * b] = w0;  gwo[2 * b + 1] = w1;
        for (int e = 0; e < NEXP; e++)
          gated[b][e] = (e == i0) ? w0 : ((e == i1) ? w1 : 0.f);
      }
      __syncthreads();
      if (t == 0) {
        float imp[NEXP] = {0.f, 0.f, 0.f, 0.f};
        for (int b = 0; b < NBAT; b++)
          for (int e = 0; e < NEXP; e++) imp[e] += gated[b][e];
        float mean = 0.f;
        for (int e = 0; e < NEXP; e++) mean += imp[e];
        mean *= 0.25f;
        float var = 0.f;
        for (int e = 0; e < NEXP; e++) { const float d = imp[e] - mean; var += d * d; }
        var *= 0.25f;
        aux[0] = var / (mean * mean + 1e-10f);
      }
    }
  } else {
    // ---- BN fold + f16 cast
    const int i = (blockIdx.x - 1024) * 256 + t;
    if (i < 32768) {                       // W1 [e][o][c], eo = i/64
      const int eo = i >> 6;
      const float inv = g1[eo] * rsqrtf(v1[eo] + 1e-5f);
      W1f[i] = (_Float16)(W1[i] * inv);
    } else if (i < 98304) {                // W2 [e][o][i], eo = j/128
      const int j = i - 32768;
      const int eo = j >> 7;
      const float inv = g2[eo] * rsqrtf(v2[eo] + 1e-5f);
      W2f[j] = (_Float16)(W2[j] * inv);
    } else if (i < 131072) {               // W3 (no BN)
      const int k = i - 98304;
      W3f[k] = (_Float16)W3[k];
    } else if (i < 131584) {               // b1'
      const int l = i - 131072;
      const float inv = g1[l] * rsqrtf(v1[l] + 1e-5f);
      b1f[l] = b1[l] * inv + be1[l] - m1[l] * inv;
    } else if (i < 132096) {               // b2'
      const int l = i - 131584;
      const float inv = g2[l] * rsqrtf(v2[l] + 1e-5f);
      b2f[l] = b2[l] * inv + be2[l] - m2[l] * inv;
    } else if (i < 132352) {               // b3'
      b3f[i - 132096] = b3[i - 132096];
    }
  }
}

// ---------------- fused top-2 expert MLP ----------------
// v5: occupancy play — LDS 73.2->51.7 KB via XOR-swizzle (no pads) + single H1
// buffer -> 3 blocks/CU (12 waves). Phase merge kept WITHOUT double-buffer:
// L3(t0) || L1(t1) touch disjoint buffers. Pin only A2 (64 VGPRs) so the
// 170-reg budget of __launch_bounds__(256,3) holds. New X-stage mapping:
// lane=position -> 256B coalesced global segments + contiguous h4 LDS writes.
__global__ __launch_bounds__(256, 3)
void moe_main_k(const float* __restrict__ x, float* __restrict__ out,
                const _Float16* __restrict__ W1f, const _Float16* __restrict__ W2f,
                const _Float16* __restrict__ W3f,
                const float* __restrict__ b1f, const float* __restrict__ b2f,
                const float* __restrict__ b3f,
                const int* __restrict__ gidx, const float* __restrict__ gwv)
{
  // rows swizzled: byte ^= (row&7)<<4  (16B-granular, bijective per 8-row stripe)
  __shared__ __align__(16) _Float16 Xs[2][64 * 64];   // [tile][pos][ch], row 128 B
  __shared__ __align__(16) _Float16 H1s[64 * 128];    // [pos][ch], row 256 B
  __shared__ __align__(16) _Float16 H2s[64 * 128];
  __shared__ __align__(16) float    bias_lds[2][320]; // [slot][b1|b2|b3]

  const int bx = blockIdx.x;
  const int b  = bx >> 7;            // sample
  const int n0 = (bx & 127) << 7;    // 128-position base
  const int t  = threadIdx.x;
  const int w  = t >> 6;
  const int lane = t & 63;
  const int ln = lane & 15;   // MFMA n / m lane index
  const int q  = lane >> 4;   // quad
  const int mh = w >> 1;      // out-channel half
  const int nh = w & 1;       // position half

  const int   ea0 = gidx[2 * b], ea1 = gidx[2 * b + 1];
  const float wa0 = gwv[2 * b],  wa1 = gwv[2 * b + 1];

  // ---- stage biases for both slots into LDS
  for (int i = t; i < 640; i += 256) {
    const int sl = i >= 320;
    const int j  = i - (sl ? 320 : 0);
    const int e  = sl ? ea1 : ea0;
    float v;
    if (j < 128)      v = b1f[e * HIDd + j];
    else if (j < 256) v = b2f[e * HIDd + (j - 128)];
    else              v = b3f[e * Cdim + (j - 256)];
    bias_lds[sl][j] = v;
  }

  // ---- stage BOTH X tiles (lane = position: 256B global segments, h4 LDS writes)
  {
    const int pos = t & 63;
    const int cb  = (t >> 6) << 4;   // 16-channel group base
    const int sw  = (pos & 7) << 4;
    const float* xb = x + (size_t)b * (Cdim * HWsz) + n0 + pos;
#pragma unroll
    for (int tt = 0; tt < 2; tt++) {
      const float* xc = xb + (tt << 6);
#pragma unroll
      for (int j = 0; j < 4; j++) {
        const int c = cb + (j << 2);
        const float v0 = xc[(size_t)(c + 0) * HWsz];
        const float v1 = xc[(size_t)(c + 1) * HWsz];
        const float v2 = xc[(size_t)(c + 2) * HWsz];
        const float v3 = xc[(size_t)(c + 3) * HWsz];
        h4 hv; hv[0] = (_Float16)v0; hv[1] = (_Float16)v1;
               hv[2] = (_Float16)v2; hv[3] = (_Float16)v3;
        *(h4*)((char*)&Xs[tt][0] + pos * 128 + (((c << 1)) ^ sw)) = hv;
      }
    }
  }

  f4 oacc[2][2][2];   // [tile][mi][ni]
#pragma unroll
  for (int tt = 0; tt < 2; tt++)
#pragma unroll
    for (int i = 0; i < 2; i++)
#pragma unroll
      for (int j = 0; j < 2; j++)
        oacc[tt][i][j] = f4{0.f, 0.f, 0.f, 0.f};

  __syncthreads();   // X + biases staged

#pragma unroll 1
  for (int slot = 0; slot < 2; slot++) {
    const int   e  = slot ? ea1 : ea0;
    const float we = slot ? wa1 : wa0;
    const _Float16* w1 = W1f + e * (HIDd * Cdim);
    const _Float16* w2 = W2f + e * (HIDd * HIDd);
    const _Float16* w3 = W3f + e * (Cdim * HIDd);

    // ---- weight fragments: A2 pinned (64 VGPRs); A1/A3 free to sink
    f4 A1[4][2], A2[4][4], A3[2][4];
#pragma unroll
    for (int mi = 0; mi < 4; mi++) {
      const int m0 = (((mh << 2) + mi) << 4);
      const _Float16* p1 = w1 + (m0 + ln) * Cdim + q * 8;
      A1[mi][0] = *(const f4*)(p1);
      A1[mi][1] = *(const f4*)(p1 + 32);
      const _Float16* p2 = w2 + (m0 + ln) * HIDd + q * 8;
#pragma unroll
      for (int ks = 0; ks < 4; ks++) A2[mi][ks] = *(const f4*)(p2 + ks * 32);
    }
#pragma unroll
    for (int mi = 0; mi < 2; mi++) {
      const int m0 = (((mh << 1) + mi) << 4);
      const _Float16* p3 = w3 + (m0 + ln) * HIDd + q * 8;
#pragma unroll
      for (int ks = 0; ks < 4; ks++) A3[mi][ks] = *(const f4*)(p3 + ks * 32);
    }
#pragma unroll
    for (int mi = 0; mi < 4; mi++)
#pragma unroll
      for (int ks = 0; ks < 4; ks++) pinv(A2[mi][ks]);

    // ---- layer bodies (all LDS addresses XOR-swizzled) ----
    auto L1 = [&](int tb) {
#pragma unroll
      for (int ni = 0; ni < 2; ni++) {
        const int nrow = ((nh << 1) + ni) * 16 + ln;
        const int sw = (nrow & 7) << 4;
        const h8 bf0 = *(const h8*)((const char*)&Xs[tb][0] + nrow * 128 + ((q * 16) ^ sw));
        const h8 bf1 = *(const h8*)((const char*)&Xs[tb][0] + nrow * 128 + ((64 + q * 16) ^ sw));
        __builtin_amdgcn_s_setprio(1);
#pragma unroll
        for (int mi = 0; mi < 4; mi++) {
          const int m0 = (((mh << 2) + mi) << 4);
          f4 acc = {0.f, 0.f, 0.f, 0.f};
          acc = __builtin_amdgcn_mfma_f32_16x16x32_f16(__builtin_bit_cast(h8, A1[mi][0]), bf0, acc, 0, 0, 0);
          acc = __builtin_amdgcn_mfma_f32_16x16x32_f16(__builtin_bit_cast(h8, A1[mi][1]), bf1, acc, 0, 0, 0);
          const f4 bias = *(const f4*)&bias_lds[slot][m0 + q * 4];
          h4 hv;
#pragma unroll
          for (int r = 0; r < 4; r++) hv[r] = (_Float16)fmaxf(acc[r] + bias[r], 0.f);
          *(h4*)((char*)H1s + nrow * 256 + (((m0 << 1) + (q << 3)) ^ sw)) = hv;
        }
        __builtin_amdgcn_s_setprio(0);
      }
    };
    auto L2 = [&]() {
#pragma unroll
      for (int ni = 0; ni < 2; ni++) {
        const int nrow = ((nh << 1) + ni) * 16 + ln;
        const int sw = (nrow & 7) << 4;
        h8 bf[4];
#pragma unroll
        for (int ks = 0; ks < 4; ks++)
          bf[ks] = *(const h8*)((const char*)H1s + nrow * 256 + (((ks << 6) + (q << 4)) ^ sw));
        __builtin_amdgcn_s_setprio(1);
#pragma unroll
        for (int mi = 0; mi < 4; mi++) {
          const int m0 = (((mh << 2) + mi) << 4);
          f4 acc = {0.f, 0.f, 0.f, 0.f};
#pragma unroll
          for (int ks = 0; ks < 4; ks++)
            acc = __builtin_amdgcn_mfma_f32_16x16x32_f16(__builtin_bit_cast(h8, A2[mi][ks]), bf[ks], acc, 0, 0, 0);
          const f4 bias = *(const f4*)&bias_lds[slot][128 + m0 + q * 4];
          h4 hv;
#pragma unroll
          for (int r = 0; r < 4; r++) hv[r] = (_Float16)fmaxf(acc[r] + bias[r], 0.f);
          *(h4*)((char*)H2s + nrow * 256 + (((m0 << 1) + (q << 3)) ^ sw)) = hv;
        }
        __builtin_amdgcn_s_setprio(0);
      }
    };
    auto L3 = [&](int tb) {
#pragma unroll
      for (int ni = 0; ni < 2; ni++) {
        const int nrow = ((nh << 1) + ni) * 16 + ln;
        const int sw = (nrow & 7) << 4;
        h8 bf[4];
#pragma unroll
        for (int ks = 0; ks < 4; ks++)
          bf[ks] = *(const h8*)((const char*)H2s + nrow * 256 + (((ks << 6) + (q << 4)) ^ sw));
        __builtin_amdgcn_s_setprio(1);
#pragma unroll
        for (int mi = 0; mi < 2; mi++) {
          const int m0 = (((mh << 1) + mi) << 4);
          f4 acc = {0.f, 0.f, 0.f, 0.f};
#pragma unroll
          for (int ks = 0; ks < 4; ks++)
            acc = __builtin_amdgcn_mfma_f32_16x16x32_f16(__builtin_bit_cast(h8, A3[mi][ks]), bf[ks], acc, 0, 0, 0);
          const f4 bias = *(const f4*)&bias_lds[slot][256 + m0 + q * 4];
#pragma unroll
          for (int r = 0; r < 4; r++) oacc[tb][mi][ni][r] += we * (acc[r] + bias[r]);
        }
        __builtin_amdgcn_s_setprio(0);
      }
    };

    // ---- 5-phase schedule, single H1/H2 buffers
    L1(0);             // P1: Xs[0] -> H1
    __syncthreads();
    L2();              // P2: H1 -> H2
    __syncthreads();
    L3(0); L1(1);      // P3 (fat): H2 -> oacc[0]  ||  Xs[1] -> H1 (H1 free since P2)
    __syncthreads();
    L2();              // P4: H1 -> H2 (H2 free: last reader L3(0) pre-barrier)
    __syncthreads();
    L3(1);             // P5: H2 -> oacc[1]
    __syncthreads();   // slot end: next slot's L2 rewrites H2 (read in P5)
  }

  // ---- store output (fp32, nontemporal streaming)
#pragma unroll
  for (int tl = 0; tl < 2; tl++)
#pragma unroll
    for (int mi = 0; mi < 2; mi++)
#pragma unroll
      for (int ni = 0; ni < 2; ni++) {
        const int c = ((mh << 1) + mi) * 16 + q * 4;
        const int n = n0 + (tl << 6) + ((nh << 1) + ni) * 16 + ln;
#pragma unroll
        for (int r = 0; r < 4; r++)
          __builtin_nontemporal_store(oacc[tl][mi][ni][r],
                                      &out[((size_t)(b * Cdim + c + r)) * HWsz + n]);
      }
}

extern "C" void kernel_launch(void* const* d_in, const int* in_sizes, int n_in,
                              void* d_out, int out_size, void* d_ws, size_t ws_size,
                              hipStream_t stream)
{
  const float* x   = (const float*)d_in[0];
  const float* W1  = (const float*)d_in[1];
  const float* b1  = (const float*)d_in[2];
  const float* g1  = (const float*)d_in[3];
  const float* be1 = (const float*)d_in[4];
  const float* m1  = (const float*)d_in[5];
  const float* v1  = (const float*)d_in[6];
  const float* W2  = (const float*)d_in[7];
  const float* b2  = (const float*)d_in[8];
  const float* g2  = (const float*)d_in[9];
  const float* be2 = (const float*)d_in[10];
  const float* m2  = (const float*)d_in[11];
  const float* v2  = (const float*)d_in[12];
  const float* W3  = (const float*)d_in[13];
  const float* b3  = (const float*)d_in[14];
  const float* gwt = (const float*)d_in[15];
  const float* gb  = (const float*)d_in[16];

  char* ws = (char*)d_ws;
  _Float16* W1f = (_Float16*)(ws + OFF_W1F);
  _Float16* W2f = (_Float16*)(ws + OFF_W2F);
  _Float16* W3f = (_Float16*)(ws + OFF_W3F);
  float* b1f = (float*)(ws + OFF_B1F);
  float* b2f = (float*)(ws + OFF_B2F);
  float* b3f = (float*)(ws + OFF_B3F);
  float* gap = (float*)(ws + OFF_GAP);
  int*   gidx = (int*)(ws + OFF_GIDX);
  float* gwo = (float*)(ws + OFF_GW);
  int*   cnt = (int*)(ws + OFF_CNT);

  float* out = (float*)d_out;
  float* aux = out + (size_t)NBAT * Cdim * HWsz;  // d_out[16777216]

  hipMemsetAsync(cnt, 0, 4, stream);
  hipLaunchKernelGGL(prep_k, dim3(1542), dim3(256), 0, stream,
                     x, gap, W1, b1, g1, be1, m1, v1, W2, b2, g2, be2, m2, v2,
                     W3, b3, W1f, W2f, W3f, b1f, b2f, b3f,
                     gwt, gb, gidx, gwo, aux, cnt);
  hipLaunchKernelGGL(moe_main_k, dim3(2048), dim3(256), 0, stream,
                     x, out, W1f, W2f, W3f, b1f, b2f, b3f, gidx, gwo);
}

// Round 6
// 297.771 us; speedup vs baseline: 1.5709x; 1.5709x over previous
//
#include <hip/hip_runtime.h>
#include <hip/hip_bf16.h>

#define HWsz 16384
#define Cdim 64
#define HIDd 128
#define NEXP 4
#define NBAT 16

typedef _Float16 h8 __attribute__((ext_vector_type(8)));
typedef _Float16 h4 __attribute__((ext_vector_type(4)));
typedef float f4 __attribute__((ext_vector_type(4)));

// d_ws layout (bytes)
#define OFF_W1F 0        // 4*128*64 f16   = 65536 B
#define OFF_W2F 65536    // 4*128*128 f16  = 131072 B
#define OFF_W3F 196608   // 4*64*128 f16   = 65536 B
#define OFF_B1F 262144   // 4*128 f32      = 2048 B
#define OFF_B2F 264192   // 4*128 f32      = 2048 B
#define OFF_B3F 266240   // 4*64 f32       = 1024 B
#define OFF_GAP 267264   // 16*64 f32      = 4096 B
#define OFF_GIDX 271360  // 16*2 int       = 128 B
#define OFF_GW  271488   // 16*2 f32       = 128 B
#define OFF_CNT 271616   // 1 int (gap-completion counter, memset to 0 per launch)

// ---------------- prep: BN-fold/f16-cast + gap + (fused) gate ----------------
// blocks 0..1023: gap over x (b*64+c per block); the LAST gap block to finish
// also computes the gate (softmax+top2+aux) — device-scope atomics per G16.
// blocks 1024..1541: weight fold.
__global__ void prep_k(const float* __restrict__ x, float* __restrict__ gap,
                       const float* __restrict__ W1, const float* __restrict__ b1,
                       const float* __restrict__ g1, const float* __restrict__ be1,
                       const float* __restrict__ m1, const float* __restrict__ v1,
                       const float* __restrict__ W2, const float* __restrict__ b2,
                       const float* __restrict__ g2, const float* __restrict__ be2,
                       const float* __restrict__ m2, const float* __restrict__ v2,
                       const float* __restrict__ W3, const float* __restrict__ b3,
                       _Float16* __restrict__ W1f, _Float16* __restrict__ W2f,
                       _Float16* __restrict__ W3f,
                       float* __restrict__ b1f, float* __restrict__ b2f,
                       float* __restrict__ b3f,
                       const float* __restrict__ gwt, const float* __restrict__ gb,
                       int* __restrict__ gidx, float* __restrict__ gwo,
                       float* __restrict__ aux, int* __restrict__ cnt)
{
  const int t = threadIdx.x;             // 256
  if (blockIdx.x < 1024) {
    // ---- global average pool over one (b,c) row — 16 loads in flight
    const int bc = blockIdx.x;
    const float4* p4 = (const float4*)(x + (size_t)bc * HWsz);
    float s0 = 0.f, s1 = 0.f, s2 = 0.f, s3 = 0.f;
#pragma unroll
    for (int i = t; i < 4096; i += 1024) {
      const float4 a = p4[i], b4 = p4[i + 256], c4 = p4[i + 512], d4 = p4[i + 768];
      s0 += a.x + a.y + a.z + a.w;
      s1 += b4.x + b4.y + b4.z + b4.w;
      s2 += c4.x + c4.y + c4.z + c4.w;
      s3 += d4.x + d4.y + d4.z + d4.w;
    }
    float s = s0 + s1 + s2 + s3;
    for (int off = 32; off; off >>= 1) s += __shfl_down(s, off, 64);
    __shared__ float red[4];
    __shared__ int lastFlag;
    if ((t & 63) == 0) red[t >> 6] = s;
    __syncthreads();
    if (t == 0) {
      const float val = (red[0] + red[1] + red[2] + red[3]) * (1.0f / HWsz);
      __hip_atomic_store(&gap[bc], val, __ATOMIC_RELEASE, __HIP_MEMORY_SCOPE_AGENT);
      const int old = __hip_atomic_fetch_add(cnt, 1, __ATOMIC_ACQ_REL, __HIP_MEMORY_SCOPE_AGENT);
      lastFlag = (old == 1023) ? 1 : 0;
    }
    __syncthreads();
    if (lastFlag) {
      // ---- gate (runs once, in the last-finishing gap block)
      __shared__ float logits[NBAT][NEXP];
      __shared__ float gated[NBAT][NEXP];
      if (t < 64) {
        const int b = t >> 2, e = t & 3;
        float s2g = gb[e];
        for (int c = 0; c < Cdim; c++) {
          const float gv = __hip_atomic_load(&gap[b * Cdim + c], __ATOMIC_RELAXED,
                                             __HIP_MEMORY_SCOPE_AGENT);
          s2g += gv * gwt[e * Cdim + c];
        }
        logits[b][e] = s2g;
      }
      __syncthreads();
      if (t < NBAT) {
        const int b = t;
        float p[NEXP];
        float mx = logits[b][0];
        for (int e = 1; e < NEXP; e++) mx = fmaxf(mx, logits[b][e]);
        float sum = 0.f;
        for (int e = 0; e < NEXP; e++) { p[e] = expf(logits[b][e] - mx); sum += p[e]; }
        for (int e = 0; e < NEXP; e++) p[e] /= sum;
        int i0 = 0;
        for (int e = 1; e < NEXP; e++) if (p[e] > p[i0]) i0 = e;  // ties -> lower idx
        int i1 = (i0 == 0) ? 1 : 0;
        for (int e = 0; e < NEXP; e++) if (e != i0 && p[e] > p[i1]) i1 = e;
        const float s2 = p[i0] + p[i1] + 1e-8f;
        const float w0 = p[i0] / s2, w1 = p[i1] / s2;
        gidx[2 * b] = i0; gidx[2 * b + 1] = i1;
        gwo[2 * b] = w0;  gwo[2 * b + 1] = w1;
        for (int e = 0; e < NEXP; e++)
          gated[b][e] = (e == i0) ? w0 : ((e == i1) ? w1 : 0.f);
      }
      __syncthreads();
      if (t == 0) {
        float imp[NEXP] = {0.f, 0.f, 0.f, 0.f};
        for (int b = 0; b < NBAT; b++)
          for (int e = 0; e < NEXP; e++) imp[e] += gated[b][e];
        float mean = 0.f;
        for (int e = 0; e < NEXP; e++) mean += imp[e];
        mean *= 0.25f;
        float var = 0.f;
        for (int e = 0; e < NEXP; e++) { const float d = imp[e] - mean; var += d * d; }
        var *= 0.25f;
        aux[0] = var / (mean * mean + 1e-10f);
      }
    }
  } else {
    // ---- BN fold + f16 cast
    const int i = (blockIdx.x - 1024) * 256 + t;
    if (i < 32768) {                       // W1 [e][o][c], eo = i/64
      const int eo = i >> 6;
      const float inv = g1[eo] * rsqrtf(v1[eo] + 1e-5f);
      W1f[i] = (_Float16)(W1[i] * inv);
    } else if (i < 98304) {                // W2 [e][o][i], eo = j/128
      const int j = i - 32768;
      const int eo = j >> 7;
      const float inv = g2[eo] * rsqrtf(v2[eo] + 1e-5f);
      W2f[j] = (_Float16)(W2[j] * inv);
    } else if (i < 131072) {               // W3 (no BN)
      const int k = i - 98304;
      W3f[k] = (_Float16)W3[k];
    } else if (i < 131584) {               // b1'
      const int l = i - 131072;
      const float inv = g1[l] * rsqrtf(v1[l] + 1e-5f);
      b1f[l] = b1[l] * inv + be1[l] - m1[l] * inv;
    } else if (i < 132096) {               // b2'
      const int l = i - 131584;
      const float inv = g2[l] * rsqrtf(v2[l] + 1e-5f);
      b2f[l] = b2[l] * inv + be2[l] - m2[l] * inv;
    } else if (i < 132352) {               // b3'
      b3f[i - 132096] = b3[i - 132096];
    }
  }
}

// ---------------- fused top-2 expert MLP ----------------
// v6 = v5 layout minus the spill-causers (R5 lesson: launch_bounds(256,3) +
// 64 pinned VGPRs forced an 84-reg allocation -> ~700MB scratch traffic).
//  - LDS 51.7 KB (swizzled, no pads; single H1 buffer) -> 3 blocks/CU by LDS.
//  - __launch_bounds__(256,2): allocator unconstrained (~124 regs in v4) ->
//    no spill; occupancy limited by LDS at 3 blocks/CU = 12 waves/CU.
//  - NO register pinning: v4 proved the sunk-load schedule still hits 103 µs
//    at 8 waves/CU; the occupancy bump is the experiment.
__global__ __launch_bounds__(256, 2)
void moe_main_k(const float* __restrict__ x, float* __restrict__ out,
                const _Float16* __restrict__ W1f, const _Float16* __restrict__ W2f,
                const _Float16* __restrict__ W3f,
                const float* __restrict__ b1f, const float* __restrict__ b2f,
                const float* __restrict__ b3f,
                const int* __restrict__ gidx, const float* __restrict__ gwv)
{
  // rows swizzled: byte ^= (row&7)<<4  (16B-granular, bijective per 8-row stripe)
  __shared__ __align__(16) _Float16 Xs[2][64 * 64];   // [tile][pos][ch], row 128 B
  __shared__ __align__(16) _Float16 H1s[64 * 128];    // [pos][ch], row 256 B
  __shared__ __align__(16) _Float16 H2s[64 * 128];
  __shared__ __align__(16) float    bias_lds[2][320]; // [slot][b1|b2|b3]

  const int bx = blockIdx.x;
  const int b  = bx >> 7;            // sample
  const int n0 = (bx & 127) << 7;    // 128-position base
  const int t  = threadIdx.x;
  const int w  = t >> 6;
  const int lane = t & 63;
  const int ln = lane & 15;   // MFMA n / m lane index
  const int q  = lane >> 4;   // quad
  const int mh = w >> 1;      // out-channel half
  const int nh = w & 1;       // position half

  const int   ea0 = gidx[2 * b], ea1 = gidx[2 * b + 1];
  const float wa0 = gwv[2 * b],  wa1 = gwv[2 * b + 1];

  // ---- stage biases for both slots into LDS
  for (int i = t; i < 640; i += 256) {
    const int sl = i >= 320;
    const int j  = i - (sl ? 320 : 0);
    const int e  = sl ? ea1 : ea0;
    float v;
    if (j < 128)      v = b1f[e * HIDd + j];
    else if (j < 256) v = b2f[e * HIDd + (j - 128)];
    else              v = b3f[e * Cdim + (j - 256)];
    bias_lds[sl][j] = v;
  }

  // ---- stage BOTH X tiles (lane = position: 256B global segments, h4 LDS writes)
  {
    const int pos = t & 63;
    const int cb  = (t >> 6) << 4;   // 16-channel group base
    const int sw  = (pos & 7) << 4;
    const float* xb = x + (size_t)b * (Cdim * HWsz) + n0 + pos;
#pragma unroll
    for (int tt = 0; tt < 2; tt++) {
      const float* xc = xb + (tt << 6);
#pragma unroll
      for (int j = 0; j < 4; j++) {
        const int c = cb + (j << 2);
        const float v0 = xc[(size_t)(c + 0) * HWsz];
        const float v1 = xc[(size_t)(c + 1) * HWsz];
        const float v2 = xc[(size_t)(c + 2) * HWsz];
        const float v3 = xc[(size_t)(c + 3) * HWsz];
        h4 hv; hv[0] = (_Float16)v0; hv[1] = (_Float16)v1;
               hv[2] = (_Float16)v2; hv[3] = (_Float16)v3;
        *(h4*)((char*)&Xs[tt][0] + pos * 128 + (((c << 1)) ^ sw)) = hv;
      }
    }
  }

  f4 oacc[2][2][2];   // [tile][mi][ni]
#pragma unroll
  for (int tt = 0; tt < 2; tt++)
#pragma unroll
    for (int i = 0; i < 2; i++)
#pragma unroll
      for (int j = 0; j < 2; j++)
        oacc[tt][i][j] = f4{0.f, 0.f, 0.f, 0.f};

  __syncthreads();   // X + biases staged

#pragma unroll 1
  for (int slot = 0; slot < 2; slot++) {
    const int   e  = slot ? ea1 : ea0;
    const float we = slot ? wa1 : wa0;
    const _Float16* w1 = W1f + e * (HIDd * Cdim);
    const _Float16* w2 = W2f + e * (HIDd * HIDd);
    const _Float16* w3 = W3f + e * (Cdim * HIDd);

    // ---- weight fragments (unpinned; compiler schedules the loads)
    f4 A1[4][2], A2[4][4], A3[2][4];
#pragma unroll
    for (int mi = 0; mi < 4; mi++) {
      const int m0 = (((mh << 2) + mi) << 4);
      const _Float16* p1 = w1 + (m0 + ln) * Cdim + q * 8;
      A1[mi][0] = *(const f4*)(p1);
      A1[mi][1] = *(const f4*)(p1 + 32);
      const _Float16* p2 = w2 + (m0 + ln) * HIDd + q * 8;
#pragma unroll
      for (int ks = 0; ks < 4; ks++) A2[mi][ks] = *(const f4*)(p2 + ks * 32);
    }
#pragma unroll
    for (int mi = 0; mi < 2; mi++) {
      const int m0 = (((mh << 1) + mi) << 4);
      const _Float16* p3 = w3 + (m0 + ln) * HIDd + q * 8;
#pragma unroll
      for (int ks = 0; ks < 4; ks++) A3[mi][ks] = *(const f4*)(p3 + ks * 32);
    }

    // ---- layer bodies (all LDS addresses XOR-swizzled) ----
    auto L1 = [&](int tb) {
#pragma unroll
      for (int ni = 0; ni < 2; ni++) {
        const int nrow = ((nh << 1) + ni) * 16 + ln;
        const int sw = (nrow & 7) << 4;
        const h8 bf0 = *(const h8*)((const char*)&Xs[tb][0] + nrow * 128 + ((q * 16) ^ sw));
        const h8 bf1 = *(const h8*)((const char*)&Xs[tb][0] + nrow * 128 + ((64 + q * 16) ^ sw));
        __builtin_amdgcn_s_setprio(1);
#pragma unroll
        for (int mi = 0; mi < 4; mi++) {
          const int m0 = (((mh << 2) + mi) << 4);
          f4 acc = {0.f, 0.f, 0.f, 0.f};
          acc = __builtin_amdgcn_mfma_f32_16x16x32_f16(__builtin_bit_cast(h8, A1[mi][0]), bf0, acc, 0, 0, 0);
          acc = __builtin_amdgcn_mfma_f32_16x16x32_f16(__builtin_bit_cast(h8, A1[mi][1]), bf1, acc, 0, 0, 0);
          const f4 bias = *(const f4*)&bias_lds[slot][m0 + q * 4];
          h4 hv;
#pragma unroll
          for (int r = 0; r < 4; r++) hv[r] = (_Float16)fmaxf(acc[r] + bias[r], 0.f);
          *(h4*)((char*)H1s + nrow * 256 + (((m0 << 1) + (q << 3)) ^ sw)) = hv;
        }
        __builtin_amdgcn_s_setprio(0);
      }
    };
    auto L2 = [&]() {
#pragma unroll
      for (int ni = 0; ni < 2; ni++) {
        const int nrow = ((nh << 1) + ni) * 16 + ln;
        const int sw = (nrow & 7) << 4;
        h8 bf[4];
#pragma unroll
        for (int ks = 0; ks < 4; ks++)
          bf[ks] = *(const h8*)((const char*)H1s + nrow * 256 + (((ks << 6) + (q << 4)) ^ sw));
        __builtin_amdgcn_s_setprio(1);
#pragma unroll
        for (int mi = 0; mi < 4; mi++) {
          const int m0 = (((mh << 2) + mi) << 4);
          f4 acc = {0.f, 0.f, 0.f, 0.f};
#pragma unroll
          for (int ks = 0; ks < 4; ks++)
            acc = __builtin_amdgcn_mfma_f32_16x16x32_f16(__builtin_bit_cast(h8, A2[mi][ks]), bf[ks], acc, 0, 0, 0);
          const f4 bias = *(const f4*)&bias_lds[slot][128 + m0 + q * 4];
          h4 hv;
#pragma unroll
          for (int r = 0; r < 4; r++) hv[r] = (_Float16)fmaxf(acc[r] + bias[r], 0.f);
          *(h4*)((char*)H2s + nrow * 256 + (((m0 << 1) + (q << 3)) ^ sw)) = hv;
        }
        __builtin_amdgcn_s_setprio(0);
      }
    };
    auto L3 = [&](int tb) {
#pragma unroll
      for (int ni = 0; ni < 2; ni++) {
        const int nrow = ((nh << 1) + ni) * 16 + ln;
        const int sw = (nrow & 7) << 4;
        h8 bf[4];
#pragma unroll
        for (int ks = 0; ks < 4; ks++)
          bf[ks] = *(const h8*)((const char*)H2s + nrow * 256 + (((ks << 6) + (q << 4)) ^ sw));
        __builtin_amdgcn_s_setprio(1);
#pragma unroll
        for (int mi = 0; mi < 2; mi++) {
          const int m0 = (((mh << 1) + mi) << 4);
          f4 acc = {0.f, 0.f, 0.f, 0.f};
#pragma unroll
          for (int ks = 0; ks < 4; ks++)
            acc = __builtin_amdgcn_mfma_f32_16x16x32_f16(__builtin_bit_cast(h8, A3[mi][ks]), bf[ks], acc, 0, 0, 0);
          const f4 bias = *(const f4*)&bias_lds[slot][256 + m0 + q * 4];
#pragma unroll
          for (int r = 0; r < 4; r++) oacc[tb][mi][ni][r] += we * (acc[r] + bias[r]);
        }
        __builtin_amdgcn_s_setprio(0);
      }
    };

    // ---- 5-phase schedule, single H1/H2 buffers
    L1(0);             // P1: Xs[0] -> H1
    __syncthreads();
    L2();              // P2: H1 -> H2
    __syncthreads();
    L3(0); L1(1);      // P3 (fat): H2 -> oacc[0]  ||  Xs[1] -> H1 (H1 free since P2)
    __syncthreads();
    L2();              // P4: H1 -> H2 (H2 free: last reader L3(0) pre-barrier)
    __syncthreads();
    L3(1);             // P5: H2 -> oacc[1]
    __syncthreads();   // slot end: next slot's L2 rewrites H2 (read in P5)
  }

  // ---- store output (fp32, nontemporal streaming)
#pragma unroll
  for (int tl = 0; tl < 2; tl++)
#pragma unroll
    for (int mi = 0; mi < 2; mi++)
#pragma unroll
      for (int ni = 0; ni < 2; ni++) {
        const int c = ((mh << 1) + mi) * 16 + q * 4;
        const int n = n0 + (tl << 6) + ((nh << 1) + ni) * 16 + ln;
#pragma unroll
        for (int r = 0; r < 4; r++)
          __builtin_nontemporal_store(oacc[tl][mi][ni][r],
                                      &out[((size_t)(b * Cdim + c + r)) * HWsz + n]);
      }
}

extern "C" void kernel_launch(void* const* d_in, const int* in_sizes, int n_in,
                              void* d_out, int out_size, void* d_ws, size_t ws_size,
                              hipStream_t stream)
{
  const float* x   = (const float*)d_in[0];
  const float* W1  = (const float*)d_in[1];
  const float* b1  = (const float*)d_in[2];
  const float* g1  = (const float*)d_in[3];
  const float* be1 = (const float*)d_in[4];
  const float* m1  = (const float*)d_in[5];
  const float* v1  = (const float*)d_in[6];
  const float* W2  = (const float*)d_in[7];
  const float* b2  = (const float*)d_in[8];
  const float* g2  = (const float*)d_in[9];
  const float* be2 = (const float*)d_in[10];
  const float* m2  = (const float*)d_in[11];
  const float* v2  = (const float*)d_in[12];
  const float* W3  = (const float*)d_in[13];
  const float* b3  = (const float*)d_in[14];
  const float* gwt = (const float*)d_in[15];
  const float* gb  = (const float*)d_in[16];

  char* ws = (char*)d_ws;
  _Float16* W1f = (_Float16*)(ws + OFF_W1F);
  _Float16* W2f = (_Float16*)(ws + OFF_W2F);
  _Float16* W3f = (_Float16*)(ws + OFF_W3F);
  float* b1f = (float*)(ws + OFF_B1F);
  float* b2f = (float*)(ws + OFF_B2F);
  float* b3f = (float*)(ws + OFF_B3F);
  float* gap = (float*)(ws + OFF_GAP);
  int*   gidx = (int*)(ws + OFF_GIDX);
  float* gwo = (float*)(ws + OFF_GW);
  int*   cnt = (int*)(ws + OFF_CNT);

  float* out = (float*)d_out;
  float* aux = out + (size_t)NBAT * Cdim * HWsz;  // d_out[16777216]

  hipMemsetAsync(cnt, 0, 4, stream);
  hipLaunchKernelGGL(prep_k, dim3(1542), dim3(256), 0, stream,
                     x, gap, W1, b1, g1, be1, m1, v1, W2, b2, g2, be2, m2, v2,
                     W3, b3, W1f, W2f, W3f, b1f, b2f, b3f,
                     gwt, gb, gidx, gwo, aux, cnt);
  hipLaunchKernelGGL(moe_main_k, dim3(2048), dim3(256), 0, stream,
                     x, out, W1f, W2f, W3f, b1f, b2f, b3f, gidx, gwo);
}